// Round 17
// baseline (195.017 us; speedup 1.0000x reference)
//
#include <hip/hip_runtime.h>
#include <hip/hip_bf16.h>
#include <stdint.h>

#define N_TOK 8192
#define D_K   1024
#define NB    128            // block tile (BM=BN=128)
#define BKF   128            // K per tile (fp8, one MFMA K-step)
#define NT    8              // K-tiles
#define FRAG_STRIDE (8 * 64 * 32)   // bytes per 16-row group: 8 tiles x 64 lanes x 32B

typedef __attribute__((ext_vector_type(4))) int   i32x4;
typedef __attribute__((ext_vector_type(8))) int   i32x8;
typedef __attribute__((ext_vector_type(4))) float f32x4;

__global__ void zero_out_kernel(float* out) { out[0] = 0.0f; }

// fp32 -> OCP e4m3fn, RNE, with subnormal handling (inputs ~N(0,1)).
__device__ __forceinline__ unsigned int f32_to_e4m3(float x) {
  uint32_t u = __builtin_bit_cast(uint32_t, x);
  unsigned int s = (u >> 24) & 0x80u;
  float ax = __builtin_fabsf(x);
  if (ax < 0.015625f) {                    // < 2^-6: subnormal
    int q = (int)rintf(ax * 512.0f);       // 0..8 (8 -> 0x08 = 2^-6 exact)
    return s | (unsigned int)q;
  }
  uint32_t au = u & 0x7FFFFFFFu;
  uint32_t v = au + 0x7FFFFu + ((au >> 20) & 1u);   // RNE at 3 mantissa bits
  int em = (int)(v >> 20) - 960;           // rebias 127->7 (<<3)
  if (em > 0x7E) em = 0x7E;                // clamp to 448 (0x7F = NaN)
  return s | (unsigned int)em;
}

// Permuting convert: A[8192][1024] fp32 -> A'[g][t][lane][32B] fp8, where
// g = row>>4, t = k>>7, lane = (kq<<4)|lr with lr = row&15, kq = (k>>5)&3.
// An MFMA fragment (g,t) is then 2048 CONTIGUOUS bytes; lane l owns
// [l*32, l*32+32) — exactly the 16x16x128 f8f6f4 A/B operand layout.
__global__ void __launch_bounds__(256)
convert_perm_kernel(const float* __restrict__ a, const float* __restrict__ b,
                    unsigned char* __restrict__ oa,
                    unsigned char* __restrict__ ob) {
  const int id = blockIdx.x * 256 + threadIdx.x;   // 262144 total
  const int l  = id & 63;
  const int t  = (id >> 6) & 7;
  const int g  = id >> 9;
  const int row = g * 16 + (l & 15);
  const int k0  = t * BKF + (l >> 4) * 32;
  const float* pa = a + (size_t)row * D_K + k0;
  const float* pb = b + (size_t)row * D_K + k0;
  unsigned int wa_[8], wb_[8];
#pragma unroll
  for (int j = 0; j < 8; ++j) {
    float4 va = ((const float4*)pa)[j];
    float4 vb = ((const float4*)pb)[j];
    wa_[j] = f32_to_e4m3(va.x) | (f32_to_e4m3(va.y) << 8) |
             (f32_to_e4m3(va.z) << 16) | (f32_to_e4m3(va.w) << 24);
    wb_[j] = f32_to_e4m3(vb.x) | (f32_to_e4m3(vb.y) << 8) |
             (f32_to_e4m3(vb.z) << 16) | (f32_to_e4m3(vb.w) << 24);
  }
  i32x4* da = (i32x4*)(oa + (size_t)id * 32);
  i32x4* db = (i32x4*)(ob + (size_t)id * 32);
  da[0] = (i32x4){(int)wa_[0], (int)wa_[1], (int)wa_[2], (int)wa_[3]};
  da[1] = (i32x4){(int)wa_[4], (int)wa_[5], (int)wa_[6], (int)wa_[7]};
  db[0] = (i32x4){(int)wb_[0], (int)wb_[1], (int)wb_[2], (int)wb_[3]};
  db[1] = (i32x4){(int)wb_[4], (int)wb_[5], (int)wb_[6], (int)wb_[7]};
}

// Fused 128x128-tile MX-fp8 GEMM + sigmoid-contrastive loss, LDS-FREE:
// operands pre-permuted to fragment order, so each wave's frag load is
// 2 KB contiguous (per lane one aligned 32B i32x8 = 2x dwordx4, fully
// coalesced — fixes R13's scattered-row failure). No K-loop barriers;
// register double-buffer one tile ahead; waves fully independent.
__global__ void __launch_bounds__(256, 1)
sigc_kernel(const unsigned char* __restrict__ A8,
            const unsigned char* __restrict__ B8,
            const int* __restrict__ labA, const int* __restrict__ labB,
            const float* __restrict__ scale_p, const float* __restrict__ bias_p,
            float* __restrict__ out) {
  __shared__ int sLabA[NB];
  __shared__ int sLabB[NB];
  __shared__ float sPart[4];

  const int tid  = threadIdx.x;
  const int lane = tid & 63;
  const int wid  = tid >> 6;      // 0..3
  const int wr   = wid >> 1;      // 0..1 (M half: rows wr*64..)
  const int wc   = wid & 1;       // 0..1 (N half)

  // 2-D XCD region mapping on the 64x64 block grid.
  const int bid = (int)blockIdx.x;
  const int xcd = bid & 7;
  const int ii  = bid >> 3;                    // 0..511
  const int rr  = (xcd >> 1) * 16 + (ii & 15); // 0..63
  const int cc  = (xcd & 1) * 32 + (ii >> 4);  // 0..63

  if (tid < 128)      sLabA[tid] = labA[rr * NB + tid];
  else                sLabB[tid - 128] = labB[cc * NB + (tid - 128)];

  // Fragment base pointers (each 32B-aligned; frag f covers 16 rows).
  const unsigned char* aF[4];
  const unsigned char* bF[4];
#pragma unroll
  for (int f = 0; f < 4; ++f) {
    aF[f] = A8 + (size_t)(rr * 8 + wr * 4 + f) * FRAG_STRIDE + lane * 32;
    bF[f] = B8 + (size_t)(cc * 8 + wc * 4 + f) * FRAG_STRIDE + lane * 32;
  }

#define LOADT(fa, fb, T) do {                                              \
    _Pragma("unroll") for (int _f = 0; _f < 4; ++_f) {                     \
      fa[_f] = *(const i32x8*)(aF[_f] + (T) * 2048);                       \
      fb[_f] = *(const i32x8*)(bF[_f] + (T) * 2048);                       \
    } } while (0)

#define MMAT(fa, fb) do {                                                  \
    __builtin_amdgcn_s_setprio(1);                                         \
    _Pragma("unroll") for (int _mf = 0; _mf < 4; ++_mf)                    \
    _Pragma("unroll") for (int _nf = 0; _nf < 4; ++_nf)                    \
      acc[_mf][_nf] = __builtin_amdgcn_mfma_scale_f32_16x16x128_f8f6f4(    \
          fa[_mf], fb[_nf], acc[_mf][_nf], 0, 0,                           \
          0, 0x7F7F7F7F, 0, 0x7F7F7F7F);                                   \
    __builtin_amdgcn_s_setprio(0); } while (0)

  f32x4 acc[4][4];
#pragma unroll
  for (int i = 0; i < 4; ++i)
#pragma unroll
    for (int j = 0; j < 4; ++j) acc[i][j] = (f32x4){0.f, 0.f, 0.f, 0.f};

  i32x8 fA0[4], fB0[4], fA1[4], fB1[4];

  // Prologue: tile 0 fragments.
  LOADT(fA0, fB0, 0);

#pragma unroll
  for (int t2 = 0; t2 < NT / 2; ++t2) {
    const int e = 2 * t2;
    LOADT(fA1, fB1, e + 1);     // odd-tile loads fly under even MFMA
    MMAT(fA0, fB0);
    if (t2 < NT / 2 - 1) LOADT(fA0, fB0, e + 2);
    MMAT(fA1, fB1);
  }

  __syncthreads();   // publish labels before epilogue

  // Epilogue (exp2-form): per-pair loss = ln2*(max(u,0)+log2(1+2^-|u|)),
  // u = -label*logit*log2e; C/D layout: col=lane&15, row=(lane>>4)*4+r.
  const float L2E = 1.4426950408889634f;
  const float sl2e = scale_p[0] * L2E;
  const float bl2e = bias_p[0] * L2E;
  float loss = 0.0f;
  const int cBase = lane & 15;
  const int rBase = (lane >> 4) * 4;
#pragma unroll
  for (int mf = 0; mf < 4; ++mf)
#pragma unroll
    for (int nf = 0; nf < 4; ++nf) {
      const int colL = sLabB[wc * 64 + nf * 16 + cBase];
#pragma unroll
      for (int r = 0; r < 4; ++r) {
        const int rowL = sLabA[wr * 64 + mf * 16 + rBase + r];
        const float u0 = fmaf(sl2e, acc[mf][nf][r], bl2e);
        const float u = (rowL == colL) ? -u0 : u0;
        loss += fmaxf(u, 0.0f) + log2f(1.0f + exp2f(-fabsf(u)));
      }
    }

#pragma unroll
  for (int off = 32; off > 0; off >>= 1) loss += __shfl_down(loss, off, 64);
  if (lane == 0) sPart[wid] = loss;
  __syncthreads();
  if (tid == 0) {
    const float s = (sPart[0] + sPart[1]) + (sPart[2] + sPart[3]);
    atomicAdd(out, s * (0.6931471805599453f / (float)N_TOK));
  }
}

extern "C" void kernel_launch(void* const* d_in, const int* in_sizes, int n_in,
                              void* d_out, int out_size, void* d_ws, size_t ws_size,
                              hipStream_t stream) {
  const float* a  = (const float*)d_in[0];
  const float* b  = (const float*)d_in[1];
  const int*   la = (const int*)d_in[2];
  const int*   lb = (const int*)d_in[3];
  const float* sc = (const float*)d_in[4];
  const float* bi = (const float*)d_in[5];
  float* out = (float*)d_out;

  unsigned char* wa = (unsigned char*)d_ws;          // fp8 A', 8 MB
  unsigned char* wb = wa + (size_t)N_TOK * D_K;      // fp8 B', 8 MB

  zero_out_kernel<<<1, 1, 0, stream>>>(out);
  convert_perm_kernel<<<1024, 256, 0, stream>>>(a, b, wa, wb);
  const int grid = (N_TOK / NB) * (N_TOK / NB);      // 4096
  sigc_kernel<<<grid, 256, 0, stream>>>(wa, wb, la, lb, sc, bi, out);
}

// Round 18
// 159.210 us; speedup vs baseline: 1.2249x; 1.2249x over previous
//
#include <hip/hip_runtime.h>
#include <hip/hip_bf16.h>
#include <stdint.h>

#define N_TOK 8192
#define D_K   1024
#define NB    128            // block tile (BM=BN=128)
#define NT    16             // K-tiles of 64
#define GSTRIDE 32768        // bytes per 32-row group: 16 tiles x 64 lanes x 32B

typedef __attribute__((ext_vector_type(4)))  int   i32x4;
typedef __attribute__((ext_vector_type(8)))  int   i32x8;
typedef __attribute__((ext_vector_type(16))) float f32x16;

__global__ void zero_out_kernel(float* out) { out[0] = 0.0f; }

// fp32 -> OCP e4m3fn, RNE, with subnormal handling (inputs ~N(0,1)).
__device__ __forceinline__ unsigned int f32_to_e4m3(float x) {
  uint32_t u = __builtin_bit_cast(uint32_t, x);
  unsigned int s = (u >> 24) & 0x80u;
  float ax = __builtin_fabsf(x);
  if (ax < 0.015625f) {                    // < 2^-6: subnormal
    int q = (int)rintf(ax * 512.0f);       // 0..8 (8 -> 0x08 = 2^-6 exact)
    return s | (unsigned int)q;
  }
  uint32_t au = u & 0x7FFFFFFFu;
  uint32_t v = au + 0x7FFFFu + ((au >> 20) & 1u);   // RNE at 3 mantissa bits
  int em = (int)(v >> 20) - 960;           // rebias 127->7 (<<3)
  if (em > 0x7E) em = 0x7E;                // clamp to 448 (0x7F = NaN)
  return s | (unsigned int)em;
}

// Permuting convert for 32x32x64 fragment order:
// A'[g][t][lane][32B], g = row>>5, t = k>>6, lane = ((k>>5)&1)<<5 | (row&31).
// A fragment (g,t) is 2048 contiguous bytes; lane l owns bytes [l*32, +32)
// = its MFMA A/B operand (same lane-owns-32-contiguous-K pattern verified
// by R11's 16x16x128 kernel). Output writes are fully coalesced (64
// consecutive ids = one 2KB fragment); input reads are 256B-chunk strided
// (full cache lines consumed).
__global__ void __launch_bounds__(256)
convert_perm_kernel(const float* __restrict__ a, const float* __restrict__ b,
                    unsigned char* __restrict__ oa,
                    unsigned char* __restrict__ ob) {
  const int id = blockIdx.x * 256 + threadIdx.x;   // 262144 total
  const int lane = id & 63;
  const int t  = (id >> 6) & 15;
  const int g  = id >> 10;
  const int row = g * 32 + (lane & 31);
  const int k0  = t * 64 + (lane >> 5) * 32;
  const float* pa = a + (size_t)row * D_K + k0;
  const float* pb = b + (size_t)row * D_K + k0;
  unsigned int wa_[8], wb_[8];
#pragma unroll
  for (int j = 0; j < 8; ++j) {
    float4 va = ((const float4*)pa)[j];
    float4 vb = ((const float4*)pb)[j];
    wa_[j] = f32_to_e4m3(va.x) | (f32_to_e4m3(va.y) << 8) |
             (f32_to_e4m3(va.z) << 16) | (f32_to_e4m3(va.w) << 24);
    wb_[j] = f32_to_e4m3(vb.x) | (f32_to_e4m3(vb.y) << 8) |
             (f32_to_e4m3(vb.z) << 16) | (f32_to_e4m3(vb.w) << 24);
  }
  i32x4* da = (i32x4*)(oa + (size_t)id * 32);
  i32x4* db = (i32x4*)(ob + (size_t)id * 32);
  da[0] = (i32x4){(int)wa_[0], (int)wa_[1], (int)wa_[2], (int)wa_[3]};
  da[1] = (i32x4){(int)wa_[4], (int)wa_[5], (int)wa_[6], (int)wa_[7]};
  db[0] = (i32x4){(int)wb_[0], (int)wb_[1], (int)wb_[2], (int)wb_[3]};
  db[1] = (i32x4){(int)wb_[4], (int)wb_[5], (int)wb_[6], (int)wb_[7]};
}

// Fused 128x128-tile MX-fp8 GEMM + sigmoid-contrastive loss, LDS-free,
// 32x32x64 scaled MFMA. R16 post-mortem: 16x16 frag dbuf = 128 VGPRs ->
// 1 wave/SIMD -> latency exposed. 32x32 frags halve the dbuf to 64 regs
// (2 A + 2 B per tile); total ~160 -> 3 waves/SIMD. Wave tile 64x64 =
// 2x2 MFMAs; no K-loop barriers; register dbuf one tile ahead.
__global__ void __launch_bounds__(256)
sigc_kernel(const unsigned char* __restrict__ A8,
            const unsigned char* __restrict__ B8,
            const int* __restrict__ labA, const int* __restrict__ labB,
            const float* __restrict__ scale_p, const float* __restrict__ bias_p,
            float* __restrict__ out) {
  __shared__ int sLabA[NB];
  __shared__ int sLabB[NB];
  __shared__ float sPart[4];

  const int tid  = threadIdx.x;
  const int lane = tid & 63;
  const int wid  = tid >> 6;      // 0..3
  const int wr   = wid >> 1;      // 0..1 (M half)
  const int wc   = wid & 1;       // 0..1 (N half)

  // 2-D XCD region mapping on the 64x64 block grid.
  const int bid = (int)blockIdx.x;
  const int xcd = bid & 7;
  const int ii  = bid >> 3;                    // 0..511
  const int rr  = (xcd >> 1) * 16 + (ii & 15); // 0..63
  const int cc  = (xcd & 1) * 32 + (ii >> 4);  // 0..63

  if (tid < 128)      sLabA[tid] = labA[rr * NB + tid];
  else                sLabB[tid - 128] = labB[cc * NB + (tid - 128)];

  // Fragment base pointers: frag (g,t) at (g*16+t)*2048 + lane*32.
  const unsigned char* aF[2];
  const unsigned char* bF[2];
#pragma unroll
  for (int f = 0; f < 2; ++f) {
    aF[f] = A8 + (size_t)(rr * 4 + wr * 2 + f) * GSTRIDE + lane * 32;
    bF[f] = B8 + (size_t)(cc * 4 + wc * 2 + f) * GSTRIDE + lane * 32;
  }

#define LOADT(fa, fb, T) do {                                              \
    fa[0] = *(const i32x8*)(aF[0] + (T) * 2048);                           \
    fa[1] = *(const i32x8*)(aF[1] + (T) * 2048);                           \
    fb[0] = *(const i32x8*)(bF[0] + (T) * 2048);                           \
    fb[1] = *(const i32x8*)(bF[1] + (T) * 2048);                           \
  } while (0)

#define MMAT(fa, fb) do {                                                  \
    __builtin_amdgcn_s_setprio(1);                                         \
    acc00 = __builtin_amdgcn_mfma_scale_f32_32x32x64_f8f6f4(               \
        fa[0], fb[0], acc00, 0, 0, 0, 0x7F7F7F7F, 0, 0x7F7F7F7F);          \
    acc01 = __builtin_amdgcn_mfma_scale_f32_32x32x64_f8f6f4(               \
        fa[0], fb[1], acc01, 0, 0, 0, 0x7F7F7F7F, 0, 0x7F7F7F7F);          \
    acc10 = __builtin_amdgcn_mfma_scale_f32_32x32x64_f8f6f4(               \
        fa[1], fb[0], acc10, 0, 0, 0, 0x7F7F7F7F, 0, 0x7F7F7F7F);          \
    acc11 = __builtin_amdgcn_mfma_scale_f32_32x32x64_f8f6f4(               \
        fa[1], fb[1], acc11, 0, 0, 0, 0x7F7F7F7F, 0, 0x7F7F7F7F);          \
    __builtin_amdgcn_s_setprio(0); } while (0)

  f32x16 acc00 = {0}, acc01 = {0}, acc10 = {0}, acc11 = {0};

  i32x8 fA0[2], fB0[2], fA1[2], fB1[2];

  // Prologue: tile 0 fragments.
  LOADT(fA0, fB0, 0);

#pragma unroll
  for (int t2 = 0; t2 < NT / 2; ++t2) {
    const int e = 2 * t2;
    LOADT(fA1, fB1, e + 1);     // odd-tile loads fly under even MFMA
    MMAT(fA0, fB0);
    if (t2 < NT / 2 - 1) LOADT(fA0, fB0, e + 2);
    MMAT(fA1, fB1);
  }

  __syncthreads();   // publish labels before epilogue

  // Epilogue (exp2-form): per-pair loss = ln2*(max(u,0)+log2(1+2^-|u|)),
  // u = -label*logit*log2e. 32x32 C/D layout (m74/m101): col = lane&31,
  // row = (reg&3) + 8*(reg>>2) + 4*(lane>>5).
  const float L2E = 1.4426950408889634f;
  const float sl2e = scale_p[0] * L2E;
  const float bl2e = bias_p[0] * L2E;
  float loss = 0.0f;
  const int colIn = lane & 31;
  const int hi32  = lane >> 5;

#define EPI(ACC, ms, ns) do {                                              \
    const int _colL = sLabB[wc * 64 + (ns) * 32 + colIn];                  \
    _Pragma("unroll") for (int _r = 0; _r < 16; ++_r) {                    \
      const int _rowL = sLabA[wr * 64 + (ms) * 32 +                        \
                              (_r & 3) + 8 * (_r >> 2) + 4 * hi32];        \
      const float _u0 = fmaf(sl2e, ACC[_r], bl2e);                         \
      const float _u = (_rowL == _colL) ? -_u0 : _u0;                      \
      loss += fmaxf(_u, 0.0f) + log2f(1.0f + exp2f(-fabsf(_u)));           \
    } } while (0)

  EPI(acc00, 0, 0);
  EPI(acc01, 0, 1);
  EPI(acc10, 1, 0);
  EPI(acc11, 1, 1);

#pragma unroll
  for (int off = 32; off > 0; off >>= 1) loss += __shfl_down(loss, off, 64);
  if (lane == 0) sPart[wid] = loss;
  __syncthreads();
  if (tid == 0) {
    const float s = (sPart[0] + sPart[1]) + (sPart[2] + sPart[3]);
    atomicAdd(out, s * (0.6931471805599453f / (float)N_TOK));
  }
}

extern "C" void kernel_launch(void* const* d_in, const int* in_sizes, int n_in,
                              void* d_out, int out_size, void* d_ws, size_t ws_size,
                              hipStream_t stream) {
  const float* a  = (const float*)d_in[0];
  const float* b  = (const float*)d_in[1];
  const int*   la = (const int*)d_in[2];
  const int*   lb = (const int*)d_in[3];
  const float* sc = (const float*)d_in[4];
  const float* bi = (const float*)d_in[5];
  float* out = (float*)d_out;

  unsigned char* wa = (unsigned char*)d_ws;          // fp8 A', 8 MB
  unsigned char* wb = wa + (size_t)N_TOK * D_K;      // fp8 B', 8 MB

  zero_out_kernel<<<1, 1, 0, stream>>>(out);
  convert_perm_kernel<<<1024, 256, 0, stream>>>(a, b, wa, wb);
  const int grid = (N_TOK / NB) * (N_TOK / NB);      // 4096
  sigc_kernel<<<grid, 256, 0, stream>>>(wa, wb, la, lb, sc, bi, out);
}

// Round 19
// 105.621 us; speedup vs baseline: 1.8464x; 1.5074x over previous
//
#include <hip/hip_runtime.h>
#include <hip/hip_bf16.h>
#include <stdint.h>

#define N_TOK 8192
#define D_K   1024
#define NB    128            // block tile (BM=BN=128)
#define NT    16             // K-tiles of 64
#define GSTRIDE 32768        // bytes per 32-row group: 16 tiles x 64 lanes x 32B

typedef __attribute__((ext_vector_type(4)))  int   i32x4;
typedef __attribute__((ext_vector_type(8)))  int   i32x8;
typedef __attribute__((ext_vector_type(16))) float f32x16;

__global__ void zero_out_kernel(float* out) { out[0] = 0.0f; }

// fp32 -> OCP e4m3fn, RNE, with subnormal handling (inputs ~N(0,1)).
__device__ __forceinline__ unsigned int f32_to_e4m3(float x) {
  uint32_t u = __builtin_bit_cast(uint32_t, x);
  unsigned int s = (u >> 24) & 0x80u;
  float ax = __builtin_fabsf(x);
  if (ax < 0.015625f) {                    // < 2^-6: subnormal
    int q = (int)rintf(ax * 512.0f);       // 0..8 (8 -> 0x08 = 2^-6 exact)
    return s | (unsigned int)q;
  }
  uint32_t au = u & 0x7FFFFFFFu;
  uint32_t v = au + 0x7FFFFu + ((au >> 20) & 1u);   // RNE at 3 mantissa bits
  int em = (int)(v >> 20) - 960;           // rebias 127->7 (<<3)
  if (em > 0x7E) em = 0x7E;                // clamp to 448 (0x7F = NaN)
  return s | (unsigned int)em;
}

// LDS-staged permuting convert (fixes R17's 70us scattered-read convert):
// block = (group g of 32 rows, array sel). Reads coalesced float4 (wave =
// 1KB contiguous), scatters fp8 into 32KB LDS image of fragment layout,
// writes out coalesced 16B stores. Fragment layout: A'[g][t][lane][32B],
// t = k>>6, lane = ((k>>5)&1)<<5 | (row&31), byte = k&31.
__global__ void __launch_bounds__(256)
convert_perm_kernel(const float* __restrict__ a, const float* __restrict__ b,
                    unsigned char* __restrict__ oa,
                    unsigned char* __restrict__ ob) {
  __shared__ unsigned int P[8192];   // 32 KB
  const int blk = (int)blockIdx.x;   // 512 blocks
  const int g   = blk >> 1;
  const float* __restrict__ src = (blk & 1) ? b : a;
  unsigned char* __restrict__ dst = (blk & 1) ? ob : oa;
  const int tid = threadIdx.x;

  const float4* s4 = (const float4*)src + (size_t)g * 8192;
  // Thread tid owns k = tid*4 of every row i; LDS u32 index:
  // off/4 = (k>>6)*512 + ((k>>5)&1)*256 + row*8 + (k&31)/4.
  const int koff = (tid >> 4) * 512 + ((tid >> 3) & 1) * 256 + (tid & 7);
#pragma unroll
  for (int i = 0; i < 32; ++i) {
    float4 v = s4[i * 256 + tid];          // row i, k = tid*4 (coalesced)
    unsigned int w = f32_to_e4m3(v.x) | (f32_to_e4m3(v.y) << 8) |
                     (f32_to_e4m3(v.z) << 16) | (f32_to_e4m3(v.w) << 24);
    P[koff + i * 8] = w;
  }
  __syncthreads();
  i32x4* d4 = (i32x4*)(dst + (size_t)g * GSTRIDE);
  const i32x4* p4 = (const i32x4*)P;
#pragma unroll
  for (int i = 0; i < 8; ++i) d4[i * 256 + tid] = p4[i * 256 + tid];
}

// Fused 128x128-tile MX-fp8 GEMM + sigmoid-contrastive loss, LDS-free,
// 32x32x64 scaled MFMA (R17 structure, 88us). New single-transcendental
// epilogue: max(u,0) = (u+|u|)/2, and sum of log2(1+e) terms via product
// p = PROD(1+e) (e = 2^-|u| <= 1, 64 factors -> p <= 2^64), one log2 per
// lane. Label matches (rare) corrected linearly: softplus flips cost -u.
__global__ void __launch_bounds__(256)
sigc_kernel(const unsigned char* __restrict__ A8,
            const unsigned char* __restrict__ B8,
            const int* __restrict__ labA, const int* __restrict__ labB,
            const float* __restrict__ scale_p, const float* __restrict__ bias_p,
            float* __restrict__ out) {
  __shared__ int sLabA[NB];
  __shared__ int sLabB[NB];
  __shared__ float sPart[4];

  const int tid  = threadIdx.x;
  const int lane = tid & 63;
  const int wid  = tid >> 6;      // 0..3
  const int wr   = wid >> 1;      // 0..1 (M half)
  const int wc   = wid & 1;       // 0..1 (N half)

  // 2-D XCD region mapping on the 64x64 block grid.
  const int bid = (int)blockIdx.x;
  const int xcd = bid & 7;
  const int ii  = bid >> 3;                    // 0..511
  const int rr  = (xcd >> 1) * 16 + (ii & 15); // 0..63
  const int cc  = (xcd & 1) * 32 + (ii >> 4);  // 0..63

  if (tid < 128)      sLabA[tid] = labA[rr * NB + tid];
  else                sLabB[tid - 128] = labB[cc * NB + (tid - 128)];

  // Fragment base pointers: frag (g,t) at (g*16+t)*2048 + lane*32.
  const unsigned char* aF[2];
  const unsigned char* bF[2];
#pragma unroll
  for (int f = 0; f < 2; ++f) {
    aF[f] = A8 + (size_t)(rr * 4 + wr * 2 + f) * GSTRIDE + lane * 32;
    bF[f] = B8 + (size_t)(cc * 4 + wc * 2 + f) * GSTRIDE + lane * 32;
  }

#define LOADT(fa, fb, T) do {                                              \
    fa[0] = *(const i32x8*)(aF[0] + (T) * 2048);                           \
    fa[1] = *(const i32x8*)(aF[1] + (T) * 2048);                           \
    fb[0] = *(const i32x8*)(bF[0] + (T) * 2048);                           \
    fb[1] = *(const i32x8*)(bF[1] + (T) * 2048);                           \
  } while (0)

#define MMAT(fa, fb) do {                                                  \
    __builtin_amdgcn_s_setprio(1);                                         \
    acc00 = __builtin_amdgcn_mfma_scale_f32_32x32x64_f8f6f4(               \
        fa[0], fb[0], acc00, 0, 0, 0, 0x7F7F7F7F, 0, 0x7F7F7F7F);          \
    acc01 = __builtin_amdgcn_mfma_scale_f32_32x32x64_f8f6f4(               \
        fa[0], fb[1], acc01, 0, 0, 0, 0x7F7F7F7F, 0, 0x7F7F7F7F);          \
    acc10 = __builtin_amdgcn_mfma_scale_f32_32x32x64_f8f6f4(               \
        fa[1], fb[0], acc10, 0, 0, 0, 0x7F7F7F7F, 0, 0x7F7F7F7F);          \
    acc11 = __builtin_amdgcn_mfma_scale_f32_32x32x64_f8f6f4(               \
        fa[1], fb[1], acc11, 0, 0, 0, 0x7F7F7F7F, 0, 0x7F7F7F7F);          \
    __builtin_amdgcn_s_setprio(0); } while (0)

  f32x16 acc00 = {0}, acc01 = {0}, acc10 = {0}, acc11 = {0};

  i32x8 fA0[2], fB0[2], fA1[2], fB1[2];

  // Prologue: tile 0 fragments.
  LOADT(fA0, fB0, 0);

#pragma unroll
  for (int t2 = 0; t2 < NT / 2; ++t2) {
    const int e = 2 * t2;
    LOADT(fA1, fB1, e + 1);     // odd-tile loads fly under even MFMA
    MMAT(fA0, fB0);
    if (t2 < NT / 2 - 1) LOADT(fA0, fB0, e + 2);
    MMAT(fA1, fB1);
  }

  __syncthreads();   // publish labels before epilogue

  // Epilogue: u = logit*log2e (unflipped). Per element accumulate
  // S1 += u, S2 += |u|, p *= (1 + 2^-|u|); matches: Sm += u.
  // loss_lane = 0.5*(S1+S2) - Sm + log2(p); total scaled by ln2/N.
  // 32x32 C/D layout (m74/m101): col = lane&31,
  // row = (reg&3) + 8*(reg>>2) + 4*(lane>>5).
  const float L2E = 1.4426950408889634f;
  const float sl2e = scale_p[0] * L2E;
  const float bl2e = bias_p[0] * L2E;
  const int colIn = lane & 31;
  const int hi32  = lane >> 5;
  const int colL0 = sLabB[wc * 64 + colIn];
  const int colL1 = sLabB[wc * 64 + 32 + colIn];
  int rl0[16], rl1[16];
#pragma unroll
  for (int r = 0; r < 16; ++r) {
    const int rbase = (r & 3) + 8 * (r >> 2) + 4 * hi32;
    rl0[r] = sLabA[wr * 64 + rbase];
    rl1[r] = sLabA[wr * 64 + 32 + rbase];
  }

  float S1 = 0.f, S2 = 0.f, Sm = 0.f, p = 1.0f;
#define EPI(ACC, RL, CL) do {                                              \
    _Pragma("unroll") for (int _r = 0; _r < 16; ++_r) {                    \
      const float _u = fmaf(sl2e, ACC[_r], bl2e);                          \
      S1 += _u;                                                            \
      S2 += fabsf(_u);                                                     \
      const float _e = exp2f(-fabsf(_u));                                  \
      p = fmaf(p, _e, p);                                                  \
      if (RL[_r] == (CL)) Sm += _u;                                       \
    } } while (0)

  EPI(acc00, rl0, colL0);
  EPI(acc01, rl0, colL1);
  EPI(acc10, rl1, colL0);
  EPI(acc11, rl1, colL1);

  float loss = 0.5f * (S1 + S2) - Sm + log2f(p);

#pragma unroll
  for (int off = 32; off > 0; off >>= 1) loss += __shfl_down(loss, off, 64);
  if (lane == 0) sPart[wid] = loss;
  __syncthreads();
  if (tid == 0) {
    const float s = (sPart[0] + sPart[1]) + (sPart[2] + sPart[3]);
    atomicAdd(out, s * (0.6931471805599453f / (float)N_TOK));
  }
}

extern "C" void kernel_launch(void* const* d_in, const int* in_sizes, int n_in,
                              void* d_out, int out_size, void* d_ws, size_t ws_size,
                              hipStream_t stream) {
  const float* a  = (const float*)d_in[0];
  const float* b  = (const float*)d_in[1];
  const int*   la = (const int*)d_in[2];
  const int*   lb = (const int*)d_in[3];
  const float* sc = (const float*)d_in[4];
  const float* bi = (const float*)d_in[5];
  float* out = (float*)d_out;

  unsigned char* wa = (unsigned char*)d_ws;          // fp8 A', 8 MB
  unsigned char* wb = wa + (size_t)N_TOK * D_K;      // fp8 B', 8 MB

  zero_out_kernel<<<1, 1, 0, stream>>>(out);
  convert_perm_kernel<<<512, 256, 0, stream>>>(a, b, wa, wb);
  const int grid = (N_TOK / NB) * (N_TOK / NB);      // 4096
  sigc_kernel<<<grid, 256, 0, stream>>>(wa, wb, la, lb, sc, bi, out);
}